// Round 11
// baseline (207.945 us; speedup 1.0000x reference)
//
#include <hip/hip_runtime.h>
#include <hip/hip_bf16.h>

typedef __bf16 bf16x8 __attribute__((ext_vector_type(8)));
typedef __bf16 bf16x4 __attribute__((ext_vector_type(4)));
typedef float  f32x16 __attribute__((ext_vector_type(16)));
typedef float  f32x4  __attribute__((ext_vector_type(4)));

#define HD      2048   // H*D floats per token row
#define DH      128
#define KVT     64     // kv tile rows
#define NCH     16     // tiles per split half (1024/64)
#define NSPLIT  2
#define NROWS   32768  // Lq*H
#define KTILE_E 8192   // 64x128 bf16 (16384 B)
#define VTILE_E 8704   // 128x68 bf16 (17408 B, stride-68 rotates banks -> 2-way free)

// global_load_lds: LDS dest = wave-uniform base + lane*16 (HW); global src per-lane.
__device__ __forceinline__ void glds16(const void* g, void* l) {
    typedef const __attribute__((address_space(1))) void g_as_t;
    typedef __attribute__((address_space(3))) void l_as_t;
    __builtin_amdgcn_global_load_lds((g_as_t*)g, (l_as_t*)l, 16, 0, 0);
}

// K row-key: rows r, r+8, r+16, r+24 get keys differing by {0,2,4,6} mod 8 so
// the 4 lanes that alias under 256B row stride hit distinct bank quads.
__device__ __forceinline__ int kkey_of(int r) {
    return (r & 7) ^ (((r >> 3) & 3) << 1);
}

// ---------------------------------------------------------------------------
// Merged prepass. bid < 2048: K[kv][h][d] fp32 -> wsK tile [h][T][r][pos<<3]
// bf16 with pos = c8 ^ kkey(r).  bid >= 2048: V transpose (32x32 LDS tiles)
// -> wsV tile [h][T][dv*68 + kv] bf16 (stride 68, pad cols 64..67 unused).
// ---------------------------------------------------------------------------
__global__ __launch_bounds__(256, 4)
void prep_kv(const float* __restrict__ Kg, const float* __restrict__ Vg,
             __bf16* __restrict__ wsK, __bf16* __restrict__ wsV)
{
    __shared__ float tile[32][33];
    const int bid = blockIdx.x;
    if (bid < 2048) {
        const int kv = bid;
        const int t  = threadIdx.x;
        const int h  = t >> 4, c8 = t & 15;
        const float* src = Kg + (size_t)kv * HD + h * DH + c8 * 8;
        f32x4 a = *(const f32x4*)(src);
        f32x4 b = *(const f32x4*)(src + 4);
        bf16x8 o;
        o[0]=(__bf16)a[0]; o[1]=(__bf16)a[1]; o[2]=(__bf16)a[2]; o[3]=(__bf16)a[3];
        o[4]=(__bf16)b[0]; o[5]=(__bf16)b[1]; o[6]=(__bf16)b[2]; o[7]=(__bf16)b[3];
        const int r = kv & 63;
        __bf16* dst = wsK + ((size_t)(h * 32 + (kv >> 6)) * KTILE_E)
                          + r * 128 + ((c8 ^ kkey_of(r)) << 3);
        *(bf16x8*)dst = o;
    } else {
        const int b = bid - 2048;
        const int dvb = b & 3, kvb = (b >> 2) & 63, h = b >> 8;
        const int t = threadIdx.x;
        {
            const int kvl = t >> 3, dv4 = (t & 7) * 4;
            f32x4 v = *(const f32x4*)(Vg + (size_t)(kvb * 32 + kvl) * HD + h * DH + dvb * 32 + dv4);
            tile[kvl][dv4 + 0] = v[0]; tile[kvl][dv4 + 1] = v[1];
            tile[kvl][dv4 + 2] = v[2]; tile[kvl][dv4 + 3] = v[3];
        }
        __syncthreads();
        {
            const int dvl = t >> 3, kv4 = (t & 7) * 4;
            const int dv   = dvb * 32 + dvl;
            const int T    = kvb >> 1;
            const int kloc = (kvb & 1) * 32 + kv4;   // 0..63, 4-aligned
            bf16x4 o;
            o[0] = (__bf16)tile[kv4 + 0][dvl]; o[1] = (__bf16)tile[kv4 + 1][dvl];
            o[2] = (__bf16)tile[kv4 + 2][dvl]; o[3] = (__bf16)tile[kv4 + 3][dvl];
            __bf16* dst = wsV + ((size_t)(h * 32 + T) * VTILE_E) + dv * 68 + kloc;
            *(bf16x4*)dst = o;
        }
    }
}

// ---------------------------------------------------------------------------
// Main attention (R10 structure): 256 thr = 4 warps x 32 q = 128 q/block,
// KVT=64, 16 iters, grid 512 = 16 qblk x (16h x 2sp) -> 2 blocks/CU with
// independent barriers (phase diversity). Staging = linear glds copy of
// pre-swizzled bf16 tiles. Pair (qblk,h) merges in-kernel: both blocks store
// partials; second arrival (atomic counter, NO spinning) merges + writes O.
// ---------------------------------------------------------------------------
__global__ __launch_bounds__(256, 2)
void fmha_main(const float* __restrict__ Qg,
               const __bf16* __restrict__ wsK, const __bf16* __restrict__ wsV,
               float* __restrict__ wsO, float* __restrict__ wsML,
               int* __restrict__ cnt, float* __restrict__ Og)
{
    __shared__ __align__(16) __bf16 klds[2][KTILE_E];   // 16 KB each
    __shared__ __align__(16) __bf16 vlds[2][VTILE_E];   // 17 KB each
    __shared__ int role;

    const int tid  = threadIdx.x;
    const int lane = tid & 63;
    const int wrp  = tid >> 6;
    const int g    = lane >> 5;
    const int l31  = lane & 31;

    const int b    = blockIdx.x;
    const int grp  = b & 31;          // XCD = grp%8; qblk-siblings share KV in L2
    const int qblk = b >> 5;
    const int h    = grp >> 1;
    const int sp   = grp & 1;
    const int T0   = sp * NCH;

    const float qscale = 1.4426950408889634f * 0.08838834764831845f; // log2(e)/sqrt(128)
    const int q = qblk * 128 + wrp * 32 + l31;

    // ---- Q fragments (B-operand of QK^T): lane=q-row, d = j*16 + 8g + e
    bf16x8 qf[8];
    {
        const float* qrow = Qg + (size_t)q * HD + h * DH;
        #pragma unroll
        for (int j = 0; j < 8; ++j) {
            f32x4 a = *(const f32x4*)(qrow + j * 16 + 8 * g);
            f32x4 c = *(const f32x4*)(qrow + j * 16 + 8 * g + 4);
            bf16x8 f;
            f[0] = (__bf16)(a[0] * qscale); f[1] = (__bf16)(a[1] * qscale);
            f[2] = (__bf16)(a[2] * qscale); f[3] = (__bf16)(a[3] * qscale);
            f[4] = (__bf16)(c[0] * qscale); f[5] = (__bf16)(c[1] * qscale);
            f[6] = (__bf16)(c[2] * qscale); f[7] = (__bf16)(c[3] * qscale);
            qf[j] = f;
        }
    }

    // ---- staging: linear glds copies (wave-uniform dest chunk, lane*16 on src)
    auto stage = [&](int T, int buf) {
        const char* kt = (const char*)(wsK + (size_t)(h * 32 + T) * KTILE_E) + wrp * 1024 + lane * 16;
        char* kl = (char*)&klds[buf][0] + wrp * 1024;
        #pragma unroll
        for (int i = 0; i < 4; ++i) glds16(kt + i * 4096, kl + i * 4096);
        const char* vt = (const char*)(wsV + (size_t)(h * 32 + T) * VTILE_E) + wrp * 1024 + lane * 16;
        char* vl = (char*)&vlds[buf][0] + wrp * 1024;
        #pragma unroll
        for (int i = 0; i < 4; ++i) glds16(vt + i * 4096, vl + i * 4096);
        if (wrp == 0) glds16(vt + 16384, vl + 16384);   // bytes 16384..17407
    };

    auto sync_all = []() {
        asm volatile("s_waitcnt vmcnt(0) lgkmcnt(0)" ::: "memory");
        __builtin_amdgcn_s_barrier();
    };

    float mrun = -1e30f, lrun = 0.0f;
    f32x16 o0, o1, o2, o3;
    #pragma unroll
    for (int r = 0; r < 16; ++r) { o0[r] = 0.f; o1[r] = 0.f; o2[r] = 0.f; o3[r] = 0.f; }

    stage(T0, 0);
    sync_all();

    const int kkey = kkey_of(l31);   // rows l31 and 32+l31 share this key

    #pragma unroll 2
    for (int tt = 0; tt < NCH; ++tt) {
        const int cur = tt & 1;
        if (tt + 1 < NCH) stage(T0 + tt + 1, cur ^ 1);   // issue-early, full-iter cover

        // ---- QK^T (swapped): S^T[kv][q], 2 chained 32-kv accumulators
        f32x16 s0, s1;
        #pragma unroll
        for (int r = 0; r < 16; ++r) { s0[r] = 0.f; s1[r] = 0.f; }
        __builtin_amdgcn_s_setprio(1);
        #pragma unroll
        for (int j = 0; j < 8; ++j) {
            const int gcol = ((2 * j + g) ^ kkey) << 3;
            bf16x8 k0 = *(const bf16x8*)&klds[cur][l31 * 128 + gcol];
            s0 = __builtin_amdgcn_mfma_f32_32x32x16_bf16(k0, qf[j], s0, 0, 0, 0);
            bf16x8 k1 = *(const bf16x8*)&klds[cur][(32 + l31) * 128 + gcol];
            s1 = __builtin_amdgcn_mfma_f32_32x32x16_bf16(k1, qf[j], s1, 0, 0, 0);
        }
        __builtin_amdgcn_s_setprio(0);

        // ---- online softmax, T13 defer-max (base-2, P <= 2^8)
        float m16[8];
        #pragma unroll
        for (int r = 0; r < 8; ++r)
            m16[r] = fmaxf(fmaxf(s0[r], s0[r + 8]), fmaxf(s1[r], s1[r + 8]));
        float tmax = fmaxf(fmaxf(fmaxf(m16[0], m16[4]), fmaxf(m16[1], m16[5])),
                           fmaxf(fmaxf(m16[2], m16[6]), fmaxf(m16[3], m16[7])));
        tmax = fmaxf(tmax, __shfl_xor(tmax, 32, 64));

        if (__any(tmax > mrun + 8.0f)) {
            const float mnew  = fmaxf(mrun, tmax);
            const float alpha = __builtin_amdgcn_exp2f(mrun - mnew);
            lrun *= alpha;
            #pragma unroll
            for (int r = 0; r < 16; ++r) { o0[r]*=alpha; o1[r]*=alpha; o2[r]*=alpha; o3[r]*=alpha; }
            mrun = mnew;
        }

        #pragma unroll
        for (int r = 0; r < 16; ++r) {   // exp in place: s becomes P
            s0[r] = __builtin_amdgcn_exp2f(s0[r] - mrun);
            s1[r] = __builtin_amdgcn_exp2f(s1[r] - mrun);
        }
        float ps = 0.f;
        #pragma unroll
        for (int r = 0; r < 16; ++r) ps += s0[r] + s1[r];
        lrun += ps;

        // P -> bf16 (S^T C/D reg order == PV B-slot order, verified bijection)
        bf16x8 pf0, pf1, pf2, pf3;
        #pragma unroll
        for (int e = 0; e < 8; ++e) {
            pf0[e] = (__bf16)s0[e]; pf1[e] = (__bf16)s0[8 + e];
            pf2[e] = (__bf16)s1[e]; pf3[e] = (__bf16)s1[8 + e];
        }

        // ---- PV: O^T[dv][q] += V^T[dv][kv] * P^T[kv][q]; V rows stride 68 (2-way free)
        __builtin_amdgcn_s_setprio(1);
        #pragma unroll
        for (int bb = 0; bb < 4; ++bb) {
            const __bf16* vb = &vlds[cur][(bb * 32 + l31) * 68];
            f32x16& oo = (bb == 0) ? o0 : (bb == 1) ? o1 : (bb == 2) ? o2 : o3;
            #define PVSTEP(base, pf)                                              \
            {                                                                     \
                bf16x4 a0 = *(const bf16x4*)(vb + (base) + 4 * g);                \
                bf16x4 a1 = *(const bf16x4*)(vb + (base) + 8 + 4 * g);            \
                bf16x8 va;                                                        \
                va[0]=a0[0]; va[1]=a0[1]; va[2]=a0[2]; va[3]=a0[3];               \
                va[4]=a1[0]; va[5]=a1[1]; va[6]=a1[2]; va[7]=a1[3];               \
                oo = __builtin_amdgcn_mfma_f32_32x32x16_bf16(va, pf, oo, 0, 0, 0);\
            }
            PVSTEP(0,  pf0) PVSTEP(16, pf1) PVSTEP(32, pf2) PVSTEP(48, pf3)
            #undef PVSTEP
        }
        __builtin_amdgcn_s_setprio(0);

        if (tt + 1 < NCH) sync_all();
    }

    // ---- epilogue: store partial; second arrival of the pair merges.
    const float ltot  = lrun + __shfl_xor(lrun, 32, 64);
    const int   rowid = q * 16 + h;
    const int   pair  = qblk * 16 + h;

    float* myO = wsO + ((size_t)sp * NROWS + rowid) * 128;
    #pragma unroll
    for (int bb = 0; bb < 4; ++bb) {
        const f32x16& oo = (bb == 0) ? o0 : (bb == 1) ? o1 : (bb == 2) ? o2 : o3;
        #pragma unroll
        for (int jj = 0; jj < 4; ++jj) {
            f32x4 v;
            v[0] = oo[4*jj+0]; v[1] = oo[4*jj+1]; v[2] = oo[4*jj+2]; v[3] = oo[4*jj+3];
            *(f32x4*)(myO + bb * 32 + 8 * jj + 4 * g) = v;
        }
    }
    if (lane < 32) {
        float* ml = wsML + ((size_t)sp * NROWS + rowid) * 2;
        ml[0] = mrun;
        ml[1] = ltot;
    }
    __threadfence();              // release: partials visible before the atomic
    __syncthreads();
    if (tid == 0) role = atomicAdd(&cnt[pair], 1);
    __syncthreads();

    if (role == 1) {              // I'm second: other's partial is visible
        __threadfence();          // acquire
        const int osp = sp ^ 1;
        const float* oml = wsML + ((size_t)osp * NROWS + rowid) * 2;
        const float mo = oml[0], lo = oml[1];
        // fixed sp-order for deterministic-enough merge
        const float m0 = (sp == 0) ? mrun : mo;
        const float l0 = (sp == 0) ? ltot : lo;
        const float m1 = (sp == 0) ? mo : mrun;
        const float l1 = (sp == 0) ? lo : ltot;
        const float M  = fmaxf(m0, m1);
        const float w0 = __builtin_amdgcn_exp2f(m0 - M);
        const float w1 = __builtin_amdgcn_exp2f(m1 - M);
        const float inv = 1.0f / (l0 * w0 + l1 * w1);
        const float wm = (sp == 0) ? w0 : w1;   // weight for my registers
        const float wo = (sp == 0) ? w1 : w0;   // weight for the loaded partial
        const float* oO = wsO + ((size_t)osp * NROWS + rowid) * 128;
        float* orow = Og + (size_t)rowid * 128;
        #pragma unroll
        for (int bb = 0; bb < 4; ++bb) {
            const f32x16& oo = (bb == 0) ? o0 : (bb == 1) ? o1 : (bb == 2) ? o2 : o3;
            #pragma unroll
            for (int jj = 0; jj < 4; ++jj) {
                f32x4 v = *(const f32x4*)(oO + bb * 32 + 8 * jj + 4 * g);
                f32x4 r;
                r[0] = (oo[4*jj+0] * wm + v[0] * wo) * inv;
                r[1] = (oo[4*jj+1] * wm + v[1] * wo) * inv;
                r[2] = (oo[4*jj+2] * wm + v[2] * wo) * inv;
                r[3] = (oo[4*jj+3] * wm + v[3] * wo) * inv;
                *(f32x4*)(orow + bb * 32 + 8 * jj + 4 * g) = r;
            }
        }
    }
}

// ---------------------------------------------------------------------------
// Fallback (ws too small — not expected): R1-style single-pass kernel.
// ---------------------------------------------------------------------------
__global__ __launch_bounds__(256, 2)
void fmha_fb(const float* __restrict__ Qg, const float* __restrict__ Kg,
             const float* __restrict__ Vg, float* __restrict__ Og)
{
    __shared__ __align__(16) __bf16 klds[2][32 * 128];
    __shared__ __align__(16) __bf16 vtlds[2][DH * 36];

    const int tid  = threadIdx.x;
    const int lane = tid & 63;
    const int wrp  = tid >> 6;
    const int g    = lane >> 5;
    const int l31  = lane & 31;

    const int b    = blockIdx.x;
    const int h    = 2 * (b & 7) + ((b >> 3) >> 4);
    const int qblk = (b >> 3) & 15;

    const float qscale = 1.4426950408889634f * 0.08838834764831845f;
    const int q = qblk * 128 + wrp * 32 + l31;

    bf16x8 qf[8];
    {
        const float* qrow = Qg + (size_t)q * HD + h * DH;
        #pragma unroll
        for (int db = 0; db < 8; ++db) {
            f32x4 a = *(const f32x4*)(qrow + db * 16 + 8 * g);
            f32x4 c = *(const f32x4*)(qrow + db * 16 + 8 * g + 4);
            bf16x8 f;
            f[0] = (__bf16)(a[0] * qscale); f[1] = (__bf16)(a[1] * qscale);
            f[2] = (__bf16)(a[2] * qscale); f[3] = (__bf16)(a[3] * qscale);
            f[4] = (__bf16)(c[0] * qscale); f[5] = (__bf16)(c[1] * qscale);
            f[6] = (__bf16)(c[2] * qscale); f[7] = (__bf16)(c[3] * qscale);
            qf[db] = f;
        }
    }

    const int krow = tid >> 3, kc = tid & 7;
    const int vkv  = tid & 31, vdv0 = (tid >> 5) * 16;
    const float* kbase = Kg + (size_t)h * DH;
    const float* vbase = Vg + (size_t)h * DH;

    f32x4 kreg0, kreg1, kreg2, kreg3, vreg0, vreg1, vreg2, vreg3;

    auto stage_load = [&](int t) {
        const float* kp = kbase + (size_t)(t * 32 + krow) * HD + kc * 8;
        kreg0 = *(const f32x4*)(kp);
        kreg1 = *(const f32x4*)(kp + 4);
        kreg2 = *(const f32x4*)(kp + 64);
        kreg3 = *(const f32x4*)(kp + 68);
        const float* vp = vbase + (size_t)(t * 32 + vkv) * HD + vdv0;
        vreg0 = *(const f32x4*)(vp);
        vreg1 = *(const f32x4*)(vp + 4);
        vreg2 = *(const f32x4*)(vp + 8);
        vreg3 = *(const f32x4*)(vp + 12);
    };

    auto stage_write = [&](int buf) {
        bf16x8 k0, k1;
        k0[0]=(__bf16)kreg0[0]; k0[1]=(__bf16)kreg0[1]; k0[2]=(__bf16)kreg0[2]; k0[3]=(__bf16)kreg0[3];
        k0[4]=(__bf16)kreg1[0]; k0[5]=(__bf16)kreg1[1]; k0[6]=(__bf16)kreg1[2]; k0[7]=(__bf16)kreg1[3];
        k1[0]=(__bf16)kreg2[0]; k1[1]=(__bf16)kreg2[1]; k1[2]=(__bf16)kreg2[2]; k1[3]=(__bf16)kreg2[3];
        k1[4]=(__bf16)kreg3[0]; k1[5]=(__bf16)kreg3[1]; k1[6]=(__bf16)kreg3[2]; k1[7]=(__bf16)kreg3[3];
        const int swz = (krow & 7) << 3;
        *(bf16x8*)&klds[buf][krow * 128 + ((kc * 8) ^ swz)]      = k0;
        *(bf16x8*)&klds[buf][krow * 128 + ((kc * 8 + 64) ^ swz)] = k1;
        #pragma unroll
        for (int jj = 0; jj < 4; ++jj) {
            f32x4 vv = (jj == 0) ? vreg0 : (jj == 1) ? vreg1 : (jj == 2) ? vreg2 : vreg3;
            #pragma unroll
            for (int e = 0; e < 4; ++e)
                vtlds[buf][(vdv0 + jj * 4 + e) * 36 + vkv] = (__bf16)vv[e];
        }
    };

    float mrun = -1e30f, lrun = 0.0f;
    f32x16 o0, o1, o2, o3;
    #pragma unroll
    for (int r = 0; r < 16; ++r) { o0[r] = 0.f; o1[r] = 0.f; o2[r] = 0.f; o3[r] = 0.f; }

    stage_load(0);
    stage_write(0);

    for (int tt = 0; tt < 64; ++tt) {
        const int cur = tt & 1;
        if (tt + 1 < 64) stage_load(tt + 1);
        __syncthreads();

        f32x16 sa, sb;
        #pragma unroll
        for (int r = 0; r < 16; ++r) { sa[r] = 0.f; sb[r] = 0.f; }
        const int kswz = (l31 & 7) << 3;
        #pragma unroll
        for (int db = 0; db < 4; ++db) {
            bf16x8 kfa = *(const bf16x8*)&klds[cur][l31 * 128 + (((2*db)   * 16 + g * 8) ^ kswz)];
            sa = __builtin_amdgcn_mfma_f32_32x32x16_bf16(kfa, qf[2*db],   sa, 0, 0, 0);
            bf16x8 kfb = *(const bf16x8*)&klds[cur][l31 * 128 + (((2*db+1) * 16 + g * 8) ^ kswz)];
            sb = __builtin_amdgcn_mfma_f32_32x32x16_bf16(kfb, qf[2*db+1], sb, 0, 0, 0);
        }
        f32x16 s;
        #pragma unroll
        for (int r = 0; r < 16; ++r) s[r] = sa[r] + sb[r];

        float m8[8];
        #pragma unroll
        for (int r = 0; r < 8; ++r) m8[r] = fmaxf(s[r], s[r + 8]);
        float tmax = fmaxf(fmaxf(fmaxf(m8[0], m8[4]), fmaxf(m8[1], m8[5])),
                           fmaxf(fmaxf(m8[2], m8[6]), fmaxf(m8[3], m8[7])));
        tmax = fmaxf(tmax, __shfl_xor(tmax, 32, 64));

        if (__any(tmax > mrun + 8.0f)) {
            const float mnew  = fmaxf(mrun, tmax);
            const float alpha = __builtin_amdgcn_exp2f(mrun - mnew);
            lrun *= alpha;
            #pragma unroll
            for (int r = 0; r < 16; ++r) { o0[r] *= alpha; o1[r] *= alpha; o2[r] *= alpha; o3[r] *= alpha; }
            mrun = mnew;
        }

        float p[16];
        #pragma unroll
        for (int r = 0; r < 16; ++r) p[r] = __builtin_amdgcn_exp2f(s[r] - mrun);
        float ps0 = 0, ps1 = 0, ps2 = 0, ps3 = 0;
        #pragma unroll
        for (int r = 0; r < 4; ++r) { ps0 += p[r]; ps1 += p[r+4]; ps2 += p[r+8]; ps3 += p[r+12]; }
        lrun += ((ps0 + ps1) + (ps2 + ps3));

        bf16x8 pf0, pf1;
        #pragma unroll
        for (int e = 0; e < 8; ++e) { pf0[e] = (__bf16)p[e]; pf1[e] = (__bf16)p[8 + e]; }

        #pragma unroll
        for (int bb = 0; bb < 4; ++bb) {
            const __bf16* vb = &vtlds[cur][(bb * 32 + l31) * 36];
            bf16x4 a0 = *(const bf16x4*)(vb + 4 * g);
            bf16x4 a1 = *(const bf16x4*)(vb + 8 + 4 * g);
            bf16x8 va;
            va[0]=a0[0]; va[1]=a0[1]; va[2]=a0[2]; va[3]=a0[3];
            va[4]=a1[0]; va[5]=a1[1]; va[6]=a1[2]; va[7]=a1[3];
            f32x16& oo = (bb == 0) ? o0 : (bb == 1) ? o1 : (bb == 2) ? o2 : o3;
            oo = __builtin_amdgcn_mfma_f32_32x32x16_bf16(va, pf0, oo, 0, 0, 0);
            bf16x4 b0 = *(const bf16x4*)(vb + 16 + 4 * g);
            bf16x4 b1 = *(const bf16x4*)(vb + 24 + 4 * g);
            va[0]=b0[0]; va[1]=b0[1]; va[2]=b0[2]; va[3]=b0[3];
            va[4]=b1[0]; va[5]=b1[1]; va[6]=b1[2]; va[7]=b1[3];
            oo = __builtin_amdgcn_mfma_f32_32x32x16_bf16(va, pf1, oo, 0, 0, 0);
        }

        if (tt + 1 < 64) stage_write(cur ^ 1);
    }

    const float ltot = lrun + __shfl_xor(lrun, 32, 64);
    const float inv  = 1.0f / ltot;
    float* orow = Og + ((size_t)q * 16 + h) * 128;
    #pragma unroll
    for (int bb = 0; bb < 4; ++bb) {
        const f32x16& oo = (bb == 0) ? o0 : (bb == 1) ? o1 : (bb == 2) ? o2 : o3;
        #pragma unroll
        for (int jj = 0; jj < 4; ++jj) {
            f32x4 v;
            v[0] = oo[4*jj+0] * inv; v[1] = oo[4*jj+1] * inv;
            v[2] = oo[4*jj+2] * inv; v[3] = oo[4*jj+3] * inv;
            *(f32x4*)(orow + bb * 32 + 8 * jj + 4 * g) = v;
        }
    }
}

extern "C" void kernel_launch(void* const* d_in, const int* in_sizes, int n_in,
                              void* d_out, int out_size, void* d_ws, size_t ws_size,
                              hipStream_t stream) {
    const float* Q = (const float*)d_in[0];
    const float* K = (const float*)d_in[1];
    const float* V = (const float*)d_in[2];
    float* O = (float*)d_out;

    const size_t wsK_b = (size_t)512 * KTILE_E * 2;            // 8 MB
    const size_t wsV_b = (size_t)512 * VTILE_E * 2;            // 8.9 MB
    const size_t needO  = (size_t)NSPLIT * NROWS * 128;        // floats (32 MB)
    const size_t needML = (size_t)NSPLIT * NROWS * 2;          // floats
    const size_t cnt_b  = 256 * sizeof(int);
    const size_t need_bytes = wsK_b + wsV_b + (needO + needML) * sizeof(float) + cnt_b;

    if (ws_size >= need_bytes) {
        __bf16* wsK = (__bf16*)d_ws;
        __bf16* wsV = (__bf16*)((char*)d_ws + wsK_b);
        float*  wsO = (float*)((char*)d_ws + wsK_b + wsV_b);
        float*  wsML = wsO + needO;
        int*    cnt  = (int*)(wsML + needML);
        hipMemsetAsync(cnt, 0, cnt_b, stream);
        hipLaunchKernelGGL(prep_kv, dim3(6144), dim3(256), 0, stream, K, V, wsK, wsV);
        hipLaunchKernelGGL(fmha_main, dim3(512), dim3(256), 0, stream,
                           Q, wsK, wsV, wsO, wsML, cnt, O);
    } else {
        hipLaunchKernelGGL(fmha_fb, dim3(256), dim3(256), 0, stream, Q, K, V, O);
    }
}

// Round 12
// 71.991 us; speedup vs baseline: 2.8885x; 2.8885x over previous
//
#include <hip/hip_runtime.h>
#include <hip/hip_bf16.h>

typedef __bf16 bf16x8 __attribute__((ext_vector_type(8)));
typedef __bf16 bf16x4 __attribute__((ext_vector_type(4)));
typedef float  f32x16 __attribute__((ext_vector_type(16)));
typedef float  f32x4  __attribute__((ext_vector_type(4)));

#define HD      2048   // H*D floats per token row
#define DH      128
#define KVT     64     // kv tile rows
#define NCH     16     // tiles per split half (1024/64)
#define NSPLIT  2
#define NROWS   32768  // Lq*H
#define KTILE_E 8192   // 64x128 bf16 (16384 B)
#define VTILE_E 8704   // 128x68 bf16 (17408 B; stride-68 -> 2-way bank alias = free)

// global_load_lds: LDS dest = wave-uniform base + lane*16 (HW); global src per-lane.
__device__ __forceinline__ void glds16(const void* g, void* l) {
    typedef const __attribute__((address_space(1))) void g_as_t;
    typedef __attribute__((address_space(3))) void l_as_t;
    __builtin_amdgcn_global_load_lds((g_as_t*)g, (l_as_t*)l, 16, 0, 0);
}

// K row-key: rows r, r+8, r+16, r+24 get keys differing by {0,2,4,6} so the 4
// lanes aliasing under the 256B row stride hit disjoint bank quads.
// (R11-verified: SQ_LDS_BANK_CONFLICT halved.)
__device__ __forceinline__ int kkey_of(int r) {
    return (r & 7) ^ (((r >> 3) & 3) << 1);
}

// ---------------------------------------------------------------------------
// Merged prepass (single dispatch). bid < 2048: K[kv][h][d] fp32 -> wsK tile
// [h][T][r][(c8 ^ kkey_of(r))<<3] bf16. bid >= 2048: V 32x32 LDS transpose ->
// wsV tile [h][T][dv*68 + kv] bf16 (cols 64..67 pad).
// ---------------------------------------------------------------------------
__global__ __launch_bounds__(256, 4)
void prep_kv(const float* __restrict__ Kg, const float* __restrict__ Vg,
             __bf16* __restrict__ wsK, __bf16* __restrict__ wsV)
{
    __shared__ float tile[32][33];
    const int bid = blockIdx.x;
    if (bid < 2048) {
        const int kv = bid;
        const int t  = threadIdx.x;
        const int h  = t >> 4, c8 = t & 15;
        const float* src = Kg + (size_t)kv * HD + h * DH + c8 * 8;
        f32x4 a = *(const f32x4*)(src);
        f32x4 b = *(const f32x4*)(src + 4);
        bf16x8 o;
        o[0]=(__bf16)a[0]; o[1]=(__bf16)a[1]; o[2]=(__bf16)a[2]; o[3]=(__bf16)a[3];
        o[4]=(__bf16)b[0]; o[5]=(__bf16)b[1]; o[6]=(__bf16)b[2]; o[7]=(__bf16)b[3];
        const int r = kv & 63;
        __bf16* dst = wsK + ((size_t)(h * 32 + (kv >> 6)) * KTILE_E)
                          + r * 128 + ((c8 ^ kkey_of(r)) << 3);
        *(bf16x8*)dst = o;
    } else {
        const int b = bid - 2048;
        const int dvb = b & 3, kvb = (b >> 2) & 63, h = b >> 8;
        const int t = threadIdx.x;
        {
            const int kvl = t >> 3, dv4 = (t & 7) * 4;
            f32x4 v = *(const f32x4*)(Vg + (size_t)(kvb * 32 + kvl) * HD + h * DH + dvb * 32 + dv4);
            tile[kvl][dv4 + 0] = v[0]; tile[kvl][dv4 + 1] = v[1];
            tile[kvl][dv4 + 2] = v[2]; tile[kvl][dv4 + 3] = v[3];
        }
        __syncthreads();
        {
            const int dvl = t >> 3, kv4 = (t & 7) * 4;
            const int dv   = dvb * 32 + dvl;
            const int T    = kvb >> 1;
            const int kloc = (kvb & 1) * 32 + kv4;   // 0..63, 4-aligned
            bf16x4 o;
            o[0] = (__bf16)tile[kv4 + 0][dvl]; o[1] = (__bf16)tile[kv4 + 1][dvl];
            o[2] = (__bf16)tile[kv4 + 2][dvl]; o[3] = (__bf16)tile[kv4 + 3][dvl];
            __bf16* dst = wsV + ((size_t)(h * 32 + T) * VTILE_E) + dv * 68 + kloc;
            *(bf16x4*)dst = o;
        }
    }
}

// ---------------------------------------------------------------------------
// Main attention (R10 structure, R11 layout fixes, R10 epilogue):
// 256 thr = 4 warps x 32 q = 128 q/block, KVT=64, 16 iters, grid 512 =
// 16 qblk x (16h x 2sp) -> 2 blocks/CU with independent barriers.
// Staging = linear glds copy of pre-swizzled bf16 tiles (no cvt, no ds_write,
// no staging regs). Partial O' + (m,l) to workspace; separate combine kernel
// (R11's in-kernel merge wrecked regalloc -> scratch spill; reverted).
// ---------------------------------------------------------------------------
__global__ __launch_bounds__(256, 2)
void fmha_main(const float* __restrict__ Qg,
               const __bf16* __restrict__ wsK, const __bf16* __restrict__ wsV,
               float* __restrict__ wsO, float* __restrict__ wsML)
{
    __shared__ __align__(16) __bf16 klds[2][KTILE_E];   // 16 KB each
    __shared__ __align__(16) __bf16 vlds[2][VTILE_E];   // 17 KB each

    const int tid  = threadIdx.x;
    const int lane = tid & 63;
    const int wrp  = tid >> 6;
    const int g    = lane >> 5;
    const int l31  = lane & 31;

    const int b    = blockIdx.x;
    const int grp  = b & 31;          // XCD = grp%8; qblk-siblings share KV in L2
    const int qblk = b >> 5;
    const int h    = grp >> 1;
    const int sp   = grp & 1;
    const int T0   = sp * NCH;

    const float qscale = 1.4426950408889634f * 0.08838834764831845f; // log2(e)/sqrt(128)
    const int q = qblk * 128 + wrp * 32 + l31;

    // ---- Q fragments (B-operand of QK^T): lane=q-row, d = j*16 + 8g + e
    bf16x8 qf[8];
    {
        const float* qrow = Qg + (size_t)q * HD + h * DH;
        #pragma unroll
        for (int j = 0; j < 8; ++j) {
            f32x4 a = *(const f32x4*)(qrow + j * 16 + 8 * g);
            f32x4 c = *(const f32x4*)(qrow + j * 16 + 8 * g + 4);
            bf16x8 f;
            f[0] = (__bf16)(a[0] * qscale); f[1] = (__bf16)(a[1] * qscale);
            f[2] = (__bf16)(a[2] * qscale); f[3] = (__bf16)(a[3] * qscale);
            f[4] = (__bf16)(c[0] * qscale); f[5] = (__bf16)(c[1] * qscale);
            f[6] = (__bf16)(c[2] * qscale); f[7] = (__bf16)(c[3] * qscale);
            qf[j] = f;
        }
    }

    // ---- staging: linear glds copies (wave-uniform dest chunk, lane*16 on src)
    auto stage = [&](int T, int buf) {
        const char* kt = (const char*)(wsK + (size_t)(h * 32 + T) * KTILE_E) + wrp * 1024 + lane * 16;
        char* kl = (char*)&klds[buf][0] + wrp * 1024;
        #pragma unroll
        for (int i = 0; i < 4; ++i) glds16(kt + i * 4096, kl + i * 4096);
        const char* vt = (const char*)(wsV + (size_t)(h * 32 + T) * VTILE_E) + wrp * 1024 + lane * 16;
        char* vl = (char*)&vlds[buf][0] + wrp * 1024;
        #pragma unroll
        for (int i = 0; i < 4; ++i) glds16(vt + i * 4096, vl + i * 4096);
        if (wrp == 0) glds16(vt + 16384, vl + 16384);   // bytes 16384..17407
    };

    auto sync_all = []() {
        asm volatile("s_waitcnt vmcnt(0) lgkmcnt(0)" ::: "memory");
        __builtin_amdgcn_s_barrier();
    };

    float mrun = -1e30f, lrun = 0.0f;
    f32x16 o0, o1, o2, o3;
    #pragma unroll
    for (int r = 0; r < 16; ++r) { o0[r] = 0.f; o1[r] = 0.f; o2[r] = 0.f; o3[r] = 0.f; }

    stage(T0, 0);
    sync_all();

    const int kkey = kkey_of(l31);   // rows l31 and 32+l31 share this key

    #pragma unroll 2
    for (int tt = 0; tt < NCH; ++tt) {
        const int cur = tt & 1;
        if (tt + 1 < NCH) stage(T0 + tt + 1, cur ^ 1);   // issue-early, full-iter cover

        // ---- QK^T (swapped): S^T[kv][q], 2 chained 32-kv accumulators
        f32x16 s0, s1;
        #pragma unroll
        for (int r = 0; r < 16; ++r) { s0[r] = 0.f; s1[r] = 0.f; }
        __builtin_amdgcn_s_setprio(1);
        #pragma unroll
        for (int j = 0; j < 8; ++j) {
            const int gcol = ((2 * j + g) ^ kkey) << 3;
            bf16x8 k0 = *(const bf16x8*)&klds[cur][l31 * 128 + gcol];
            s0 = __builtin_amdgcn_mfma_f32_32x32x16_bf16(k0, qf[j], s0, 0, 0, 0);
            bf16x8 k1 = *(const bf16x8*)&klds[cur][(32 + l31) * 128 + gcol];
            s1 = __builtin_amdgcn_mfma_f32_32x32x16_bf16(k1, qf[j], s1, 0, 0, 0);
        }
        __builtin_amdgcn_s_setprio(0);

        // ---- online softmax, T13 defer-max (base-2, P <= 2^8)
        float m16[8];
        #pragma unroll
        for (int r = 0; r < 8; ++r)
            m16[r] = fmaxf(fmaxf(s0[r], s0[r + 8]), fmaxf(s1[r], s1[r + 8]));
        float tmax = fmaxf(fmaxf(fmaxf(m16[0], m16[4]), fmaxf(m16[1], m16[5])),
                           fmaxf(fmaxf(m16[2], m16[6]), fmaxf(m16[3], m16[7])));
        tmax = fmaxf(tmax, __shfl_xor(tmax, 32, 64));

        if (__any(tmax > mrun + 8.0f)) {
            const float mnew  = fmaxf(mrun, tmax);
            const float alpha = __builtin_amdgcn_exp2f(mrun - mnew);
            lrun *= alpha;
            #pragma unroll
            for (int r = 0; r < 16; ++r) { o0[r]*=alpha; o1[r]*=alpha; o2[r]*=alpha; o3[r]*=alpha; }
            mrun = mnew;
        }

        #pragma unroll
        for (int r = 0; r < 16; ++r) {   // exp in place: s becomes P
            s0[r] = __builtin_amdgcn_exp2f(s0[r] - mrun);
            s1[r] = __builtin_amdgcn_exp2f(s1[r] - mrun);
        }
        float ps = 0.f;
        #pragma unroll
        for (int r = 0; r < 16; ++r) ps += s0[r] + s1[r];
        lrun += ps;

        // P -> bf16 (S^T C/D reg order == PV B-slot order, verified bijection)
        bf16x8 pf0, pf1, pf2, pf3;
        #pragma unroll
        for (int e = 0; e < 8; ++e) {
            pf0[e] = (__bf16)s0[e]; pf1[e] = (__bf16)s0[8 + e];
            pf2[e] = (__bf16)s1[e]; pf3[e] = (__bf16)s1[8 + e];
        }

        // ---- PV: O^T[dv][q] += V^T[dv][kv] * P^T[kv][q]; V rows stride 68 (2-way free)
        __builtin_amdgcn_s_setprio(1);
        #pragma unroll
        for (int bb = 0; bb < 4; ++bb) {
            const __bf16* vb = &vlds[cur][(bb * 32 + l31) * 68];
            f32x16& oo = (bb == 0) ? o0 : (bb == 1) ? o1 : (bb == 2) ? o2 : o3;
            #define PVSTEP(base, pf)                                              \
            {                                                                     \
                bf16x4 a0 = *(const bf16x4*)(vb + (base) + 4 * g);                \
                bf16x4 a1 = *(const bf16x4*)(vb + (base) + 8 + 4 * g);            \
                bf16x8 va;                                                        \
                va[0]=a0[0]; va[1]=a0[1]; va[2]=a0[2]; va[3]=a0[3];               \
                va[4]=a1[0]; va[5]=a1[1]; va[6]=a1[2]; va[7]=a1[3];               \
                oo = __builtin_amdgcn_mfma_f32_32x32x16_bf16(va, pf, oo, 0, 0, 0);\
            }
            PVSTEP(0,  pf0) PVSTEP(16, pf1) PVSTEP(32, pf2) PVSTEP(48, pf3)
            #undef PVSTEP
        }
        __builtin_amdgcn_s_setprio(0);

        if (tt + 1 < NCH) sync_all();
    }

    // ---- epilogue: unnormalized O' + (m,l) to workspace (R10-proven codegen)
    const float ltot  = lrun + __shfl_xor(lrun, 32, 64);
    const int   rowid = q * 16 + h;

    float* orow = wsO + ((size_t)sp * NROWS + rowid) * 128;
    #pragma unroll
    for (int bb = 0; bb < 4; ++bb) {
        const f32x16& oo = (bb == 0) ? o0 : (bb == 1) ? o1 : (bb == 2) ? o2 : o3;
        #pragma unroll
        for (int jj = 0; jj < 4; ++jj) {
            f32x4 v;
            v[0] = oo[4*jj+0]; v[1] = oo[4*jj+1]; v[2] = oo[4*jj+2]; v[3] = oo[4*jj+3];
            *(f32x4*)(orow + bb * 32 + 8 * jj + 4 * g) = v;
        }
    }
    if (lane < 32) {
        float* ml = wsML + ((size_t)sp * NROWS + rowid) * 2;
        ml[0] = mrun;
        ml[1] = ltot;
    }
}

// ---------------------------------------------------------------------------
// Combine: O[row] = sum_s 2^(m_s - M) * O'_s[row] / L.
// ---------------------------------------------------------------------------
__global__ __launch_bounds__(256, 4)
void fmha_combine(const float* __restrict__ wsO, const float* __restrict__ wsML,
                  float* __restrict__ Og)
{
    const int tid   = threadIdx.x;
    const int rowid = blockIdx.x * 8 + (tid >> 5);
    const int c     = (tid & 31) * 4;

    float m[NSPLIT], l[NSPLIT];
    float M = -1e30f;
    #pragma unroll
    for (int s = 0; s < NSPLIT; ++s) {
        const float* ml = wsML + ((size_t)s * NROWS + rowid) * 2;
        m[s] = ml[0]; l[s] = ml[1];
        M = fmaxf(M, m[s]);
    }
    float L = 0.f, w[NSPLIT];
    #pragma unroll
    for (int s = 0; s < NSPLIT; ++s) {
        w[s] = __builtin_amdgcn_exp2f(m[s] - M);
        L += l[s] * w[s];
    }
    const float inv = 1.0f / L;

    f32x4 acc; acc[0]=0.f; acc[1]=0.f; acc[2]=0.f; acc[3]=0.f;
    #pragma unroll
    for (int s = 0; s < NSPLIT; ++s) {
        f32x4 v = *(const f32x4*)(wsO + ((size_t)s * NROWS + rowid) * 128 + c);
        acc[0] += v[0] * w[s]; acc[1] += v[1] * w[s];
        acc[2] += v[2] * w[s]; acc[3] += v[3] * w[s];
    }
    f32x4 r;
    r[0] = acc[0]*inv; r[1] = acc[1]*inv; r[2] = acc[2]*inv; r[3] = acc[3]*inv;
    *(f32x4*)(Og + (size_t)rowid * 128 + c) = r;
}

// ---------------------------------------------------------------------------
// Fallback (ws too small — not expected): R1-style single-pass kernel.
// ---------------------------------------------------------------------------
__global__ __launch_bounds__(256, 2)
void fmha_fb(const float* __restrict__ Qg, const float* __restrict__ Kg,
             const float* __restrict__ Vg, float* __restrict__ Og)
{
    __shared__ __align__(16) __bf16 klds[2][32 * 128];
    __shared__ __align__(16) __bf16 vtlds[2][DH * 36];

    const int tid  = threadIdx.x;
    const int lane = tid & 63;
    const int wrp  = tid >> 6;
    const int g    = lane >> 5;
    const int l31  = lane & 31;

    const int b    = blockIdx.x;
    const int h    = 2 * (b & 7) + ((b >> 3) >> 4);
    const int qblk = (b >> 3) & 15;

    const float qscale = 1.4426950408889634f * 0.08838834764831845f;
    const int q = qblk * 128 + wrp * 32 + l31;

    bf16x8 qf[8];
    {
        const float* qrow = Qg + (size_t)q * HD + h * DH;
        #pragma unroll
        for (int db = 0; db < 8; ++db) {
            f32x4 a = *(const f32x4*)(qrow + db * 16 + 8 * g);
            f32x4 c = *(const f32x4*)(qrow + db * 16 + 8 * g + 4);
            bf16x8 f;
            f[0] = (__bf16)(a[0] * qscale); f[1] = (__bf16)(a[1] * qscale);
            f[2] = (__bf16)(a[2] * qscale); f[3] = (__bf16)(a[3] * qscale);
            f[4] = (__bf16)(c[0] * qscale); f[5] = (__bf16)(c[1] * qscale);
            f[6] = (__bf16)(c[2] * qscale); f[7] = (__bf16)(c[3] * qscale);
            qf[db] = f;
        }
    }

    const int krow = tid >> 3, kc = tid & 7;
    const int vkv  = tid & 31, vdv0 = (tid >> 5) * 16;
    const float* kbase = Kg + (size_t)h * DH;
    const float* vbase = Vg + (size_t)h * DH;

    f32x4 kreg0, kreg1, kreg2, kreg3, vreg0, vreg1, vreg2, vreg3;

    auto stage_load = [&](int t) {
        const float* kp = kbase + (size_t)(t * 32 + krow) * HD + kc * 8;
        kreg0 = *(const f32x4*)(kp);
        kreg1 = *(const f32x4*)(kp + 4);
        kreg2 = *(const f32x4*)(kp + 64);
        kreg3 = *(const f32x4*)(kp + 68);
        const float* vp = vbase + (size_t)(t * 32 + vkv) * HD + vdv0;
        vreg0 = *(const f32x4*)(vp);
        vreg1 = *(const f32x4*)(vp + 4);
        vreg2 = *(const f32x4*)(vp + 8);
        vreg3 = *(const f32x4*)(vp + 12);
    };

    auto stage_write = [&](int buf) {
        bf16x8 k0, k1;
        k0[0]=(__bf16)kreg0[0]; k0[1]=(__bf16)kreg0[1]; k0[2]=(__bf16)kreg0[2]; k0[3]=(__bf16)kreg0[3];
        k0[4]=(__bf16)kreg1[0]; k0[5]=(__bf16)kreg1[1]; k0[6]=(__bf16)kreg1[2]; k0[7]=(__bf16)kreg1[3];
        k1[0]=(__bf16)kreg2[0]; k1[1]=(__bf16)kreg2[1]; k1[2]=(__bf16)kreg2[2]; k1[3]=(__bf16)kreg2[3];
        k1[4]=(__bf16)kreg3[0]; k1[5]=(__bf16)kreg3[1]; k1[6]=(__bf16)kreg3[2]; k1[7]=(__bf16)kreg3[3];
        const int swz = (krow & 7) << 3;
        *(bf16x8*)&klds[buf][krow * 128 + ((kc * 8) ^ swz)]      = k0;
        *(bf16x8*)&klds[buf][krow * 128 + ((kc * 8 + 64) ^ swz)] = k1;
        #pragma unroll
        for (int jj = 0; jj < 4; ++jj) {
            f32x4 vv = (jj == 0) ? vreg0 : (jj == 1) ? vreg1 : (jj == 2) ? vreg2 : vreg3;
            #pragma unroll
            for (int e = 0; e < 4; ++e)
                vtlds[buf][(vdv0 + jj * 4 + e) * 36 + vkv] = (__bf16)vv[e];
        }
    };

    float mrun = -1e30f, lrun = 0.0f;
    f32x16 o0, o1, o2, o3;
    #pragma unroll
    for (int r = 0; r < 16; ++r) { o0[r] = 0.f; o1[r] = 0.f; o2[r] = 0.f; o3[r] = 0.f; }

    stage_load(0);
    stage_write(0);

    for (int tt = 0; tt < 64; ++tt) {
        const int cur = tt & 1;
        if (tt + 1 < 64) stage_load(tt + 1);
        __syncthreads();

        f32x16 sa, sb;
        #pragma unroll
        for (int r = 0; r < 16; ++r) { sa[r] = 0.f; sb[r] = 0.f; }
        const int kswz = (l31 & 7) << 3;
        #pragma unroll
        for (int db = 0; db < 4; ++db) {
            bf16x8 kfa = *(const bf16x8*)&klds[cur][l31 * 128 + (((2*db)   * 16 + g * 8) ^ kswz)];
            sa = __builtin_amdgcn_mfma_f32_32x32x16_bf16(kfa, qf[2*db],   sa, 0, 0, 0);
            bf16x8 kfb = *(const bf16x8*)&klds[cur][l31 * 128 + (((2*db+1) * 16 + g * 8) ^ kswz)];
            sb = __builtin_amdgcn_mfma_f32_32x32x16_bf16(kfb, qf[2*db+1], sb, 0, 0, 0);
        }
        f32x16 s;
        #pragma unroll
        for (int r = 0; r < 16; ++r) s[r] = sa[r] + sb[r];

        float m8[8];
        #pragma unroll
        for (int r = 0; r < 8; ++r) m8[r] = fmaxf(s[r], s[r + 8]);
        float tmax = fmaxf(fmaxf(fmaxf(m8[0], m8[4]), fmaxf(m8[1], m8[5])),
                           fmaxf(fmaxf(m8[2], m8[6]), fmaxf(m8[3], m8[7])));
        tmax = fmaxf(tmax, __shfl_xor(tmax, 32, 64));

        if (__any(tmax > mrun + 8.0f)) {
            const float mnew  = fmaxf(mrun, tmax);
            const float alpha = __builtin_amdgcn_exp2f(mrun - mnew);
            lrun *= alpha;
            #pragma unroll
            for (int r = 0; r < 16; ++r) { o0[r] *= alpha; o1[r] *= alpha; o2[r] *= alpha; o3[r] *= alpha; }
            mrun = mnew;
        }

        float p[16];
        #pragma unroll
        for (int r = 0; r < 16; ++r) p[r] = __builtin_amdgcn_exp2f(s[r] - mrun);
        float ps0 = 0, ps1 = 0, ps2 = 0, ps3 = 0;
        #pragma unroll
        for (int r = 0; r < 4; ++r) { ps0 += p[r]; ps1 += p[r+4]; ps2 += p[r+8]; ps3 += p[r+12]; }
        lrun += ((ps0 + ps1) + (ps2 + ps3));

        bf16x8 pf0, pf1;
        #pragma unroll
        for (int e = 0; e < 8; ++e) { pf0[e] = (__bf16)p[e]; pf1[e] = (__bf16)p[8 + e]; }

        #pragma unroll
        for (int bb = 0; bb < 4; ++bb) {
            const __bf16* vb = &vtlds[cur][(bb * 32 + l31) * 36];
            bf16x4 a0 = *(const bf16x4*)(vb + 4 * g);
            bf16x4 a1 = *(const bf16x4*)(vb + 8 + 4 * g);
            bf16x8 va;
            va[0]=a0[0]; va[1]=a0[1]; va[2]=a0[2]; va[3]=a0[3];
            va[4]=a1[0]; va[5]=a1[1]; va[6]=a1[2]; va[7]=a1[3];
            f32x16& oo = (bb == 0) ? o0 : (bb == 1) ? o1 : (bb == 2) ? o2 : o3;
            oo = __builtin_amdgcn_mfma_f32_32x32x16_bf16(va, pf0, oo, 0, 0, 0);
            bf16x4 b0 = *(const bf16x4*)(vb + 16 + 4 * g);
            bf16x4 b1 = *(const bf16x4*)(vb + 24 + 4 * g);
            va[0]=b0[0]; va[1]=b0[1]; va[2]=b0[2]; va[3]=b0[3];
            va[4]=b1[0]; va[5]=b1[1]; va[6]=b1[2]; va[7]=b1[3];
            oo = __builtin_amdgcn_mfma_f32_32x32x16_bf16(va, pf1, oo, 0, 0, 0);
        }

        if (tt + 1 < 64) stage_write(cur ^ 1);
    }

    const float ltot = lrun + __shfl_xor(lrun, 32, 64);
    const float inv  = 1.0f / ltot;
    float* orow = Og + ((size_t)q * 16 + h) * 128;
    #pragma unroll
    for (int bb = 0; bb < 4; ++bb) {
        const f32x16& oo = (bb == 0) ? o0 : (bb == 1) ? o1 : (bb == 2) ? o2 : o3;
        #pragma unroll
        for (int jj = 0; jj < 4; ++jj) {
            f32x4 v;
            v[0] = oo[4*jj+0] * inv; v[1] = oo[4*jj+1] * inv;
            v[2] = oo[4*jj+2] * inv; v[3] = oo[4*jj+3] * inv;
            *(f32x4*)(orow + bb * 32 + 8 * jj + 4 * g) = v;
        }
    }
}

extern "C" void kernel_launch(void* const* d_in, const int* in_sizes, int n_in,
                              void* d_out, int out_size, void* d_ws, size_t ws_size,
                              hipStream_t stream) {
    const float* Q = (const float*)d_in[0];
    const float* K = (const float*)d_in[1];
    const float* V = (const float*)d_in[2];
    float* O = (float*)d_out;

    const size_t wsK_b = (size_t)512 * KTILE_E * 2;            // 8 MB
    const size_t wsV_b = (size_t)512 * VTILE_E * 2;            // 8.9 MB
    const size_t needO  = (size_t)NSPLIT * NROWS * 128;        // floats (32 MB)
    const size_t needML = (size_t)NSPLIT * NROWS * 2;          // floats
    const size_t need_bytes = wsK_b + wsV_b + (needO + needML) * sizeof(float);

    if (ws_size >= need_bytes) {
        __bf16* wsK = (__bf16*)d_ws;
        __bf16* wsV = (__bf16*)((char*)d_ws + wsK_b);
        float*  wsO = (float*)((char*)d_ws + wsK_b + wsV_b);
        float*  wsML = wsO + needO;
        hipLaunchKernelGGL(prep_kv, dim3(6144), dim3(256), 0, stream, K, V, wsK, wsV);
        hipLaunchKernelGGL(fmha_main, dim3(512), dim3(256), 0, stream,
                           Q, wsK, wsV, wsO, wsML);
        hipLaunchKernelGGL(fmha_combine, dim3(NROWS / 8), dim3(256), 0, stream,
                           wsO, wsML, O);
    } else {
        hipLaunchKernelGGL(fmha_fb, dim3(256), dim3(256), 0, stream, Q, K, V, O);
    }
}